// Round 2
// baseline (287.707 us; speedup 1.0000x reference)
//
#include <hip/hip_runtime.h>
#include <stdint.h>

#define NH 16
#define NDV 64
#define NDM 1024
#define NB 8
#define NL 1024

typedef __attribute__((ext_vector_type(8))) short short8;
typedef __attribute__((ext_vector_type(4))) short short4v;
typedef __attribute__((ext_vector_type(4))) float f32x4;

static __device__ __forceinline__ unsigned short f2bf(float x) {
    unsigned int u = __builtin_bit_cast(unsigned int, x);
    unsigned int r = (u + 0x7fffu + ((u >> 16) & 1u)) >> 16;
    return (unsigned short)r;
}

static __device__ __forceinline__ float waveMax(float v) {
#pragma unroll
    for (int o = 32; o > 0; o >>= 1) v = fmaxf(v, __shfl_xor(v, o, 64));
    return v;
}
static __device__ __forceinline__ float waveSum(float v) {
#pragma unroll
    for (int o = 32; o > 0; o >>= 1) v += __shfl_xor(v, o, 64);
    return v;
}

// async global->LDS, 16B per lane (wave writes 1KB contiguous at ldsptr)
static __device__ __forceinline__ void gload_lds16(const void* g, void* l) {
    __builtin_amdgcn_global_load_lds((const __attribute__((address_space(1))) void*)g,
                                     (__attribute__((address_space(3))) void*)l, 16, 0, 0);
}

// ---------------- fused fp32 -> bf16 converts (v, w_v, w_fc) ----------------
__global__ __launch_bounds__(256) void cvt3(const float* __restrict__ v,
                                            const float* __restrict__ wv,
                                            const float* __restrict__ wfc,
                                            unsigned short* __restrict__ v_bf,
                                            unsigned short* __restrict__ wv_bf,
                                            unsigned short* __restrict__ wfc_bf) {
    int b = blockIdx.x;
    const float* src;
    unsigned short* dst;
    if (b < 8192)      { src = v;   dst = v_bf; }
    else if (b < 9216) { src = wv;  dst = wv_bf;  b -= 8192; }
    else               { src = wfc; dst = wfc_bf; b -= 9216; }
    const size_t idx = ((size_t)b * 256 + threadIdx.x) << 2;
    const float4 x = *(const float4*)(src + idx);
    short4v u;
    u[0] = (short)f2bf(x.x); u[1] = (short)f2bf(x.y);
    u[2] = (short)f2bf(x.z); u[3] = (short)f2bf(x.w);
    *(short4v*)(dst + idx) = u;
}

// ---------------- 128x128 MFMA GEMM core: C = A[M,K] @ Bt[N,K]^T ----------------
// global_load_lds(16B) staging, linear LDS [128][32] with chunk-XOR swizzle
// (swizzle applied to global SOURCE addr + ds_read addr; LDS dest stays linear).
// EPI=1: +bias, bf16 scatter to vvT[h][b*64+d][l]
// EPI=2: bf16 scatter to X[(b*1024+q)][bh*64+d]
// EPI=3: +bias, fp32 row-major
template <int EPI>
static __device__ __forceinline__ void gemm128_core(
    const unsigned short* __restrict__ A,
    const unsigned short* __restrict__ Bt,
    const float* __restrict__ bias,
    void* __restrict__ Cout,
    const int K, const int tm, const int tn, const int bh,
    unsigned short* sA, unsigned short* sB) {
    const int tid = threadIdx.x;
    const int lane = tid & 63;
    const int w = tid >> 6;
    const int wr = w >> 1, wc = w & 1;

    const unsigned short* Ab = A + (size_t)tm * 128 * K;
    const unsigned short* Bb = Bt + (size_t)tn * 128 * K;

    // staging: wave w covers rows [w*32, w*32+32); lane -> row r0(+16), chunk=lane&3
    const int r0 = w * 32 + (lane >> 2);
    const int ch = lane & 3;
    const int so = ((ch ^ ((r0 >> 1) & 3)) << 3);  // pre-swizzled source col (shorts)
    const unsigned short* gA0 = Ab + (size_t)r0 * K + so;
    const unsigned short* gA1 = Ab + (size_t)(r0 + 16) * K + so;  // same swizzle key (bit4 change)
    const unsigned short* gB0 = Bb + (size_t)r0 * K + so;
    const unsigned short* gB1 = Bb + (size_t)(r0 + 16) * K + so;
    unsigned short* lA0 = sA + w * 1024;
    unsigned short* lA1 = lA0 + 512;
    unsigned short* lB0 = sB + w * 1024;
    unsigned short* lB1 = lB0 + 512;

    // fragment ds_read offsets (swizzled)
    const int c = lane >> 4;
    int offA[4], offB[4];
#pragma unroll
    for (int f = 0; f < 4; ++f) {
        const int fra = wr * 64 + f * 16 + (lane & 15);
        offA[f] = fra * 32 + ((c ^ ((fra >> 1) & 3)) << 3);
        const int frb = wc * 64 + f * 16 + (lane & 15);
        offB[f] = frb * 32 + ((c ^ ((frb >> 1) & 3)) << 3);
    }

    f32x4 acc[4][4];
#pragma unroll
    for (int i = 0; i < 4; ++i)
#pragma unroll
        for (int j = 0; j < 4; ++j) acc[i][j] = (f32x4){0.f, 0.f, 0.f, 0.f};

    for (int kt = 0; kt < K; kt += 32) {
        __syncthreads();  // readers done with LDS
        gload_lds16(gA0 + kt, lA0);
        gload_lds16(gA1 + kt, lA1);
        gload_lds16(gB0 + kt, lB0);
        gload_lds16(gB1 + kt, lB1);
        __syncthreads();  // compiler drains vmcnt(0) before barrier

        short8 af[4], bfv[4];
#pragma unroll
        for (int f = 0; f < 4; ++f) af[f] = *(const short8*)&sA[offA[f]];
#pragma unroll
        for (int f = 0; f < 4; ++f) bfv[f] = *(const short8*)&sB[offB[f]];
#pragma unroll
        for (int i = 0; i < 4; ++i)
#pragma unroll
            for (int j = 0; j < 4; ++j)
                acc[i][j] = __builtin_amdgcn_mfma_f32_16x16x32_bf16(af[i], bfv[j], acc[i][j], 0, 0, 0);
    }

#pragma unroll
    for (int i = 0; i < 4; ++i) {
        const int gRow0 = tm * 128 + wr * 64 + i * 16 + ((lane >> 4) << 2);
#pragma unroll
        for (int j = 0; j < 4; ++j) {
            const int gCol = tn * 128 + wc * 64 + j * 16 + (lane & 15);
            f32x4 v = acc[i][j];
            if (EPI == 1) {
                const float bb2 = bias[gCol];
                const int hh = gCol >> 6, dd = gCol & 63;
                const int b = gRow0 >> 10, ll2 = gRow0 & 1023;
                unsigned short* C = (unsigned short*)Cout;
                short4v u;
                u[0] = (short)f2bf(v[0] + bb2);
                u[1] = (short)f2bf(v[1] + bb2);
                u[2] = (short)f2bf(v[2] + bb2);
                u[3] = (short)f2bf(v[3] + bb2);
                *(short4v*)(C + (size_t)hh * 524288 + ((size_t)b * 64 + dd) * 1024 + ll2) = u;
            } else if (EPI == 2) {
                const int b = gCol >> 6, dd = gCol & 63;
                unsigned short* X = (unsigned short*)Cout;
#pragma unroll
                for (int r = 0; r < 4; ++r)
                    X[((size_t)b * 1024 + gRow0 + r) * 1024 + bh * 64 + dd] = f2bf(v[r]);
            } else {
                const float bb2 = bias[gCol];
                float* O = (float*)Cout;
#pragma unroll
                for (int r = 0; r < 4; ++r)
                    O[(size_t)(gRow0 + r) * 1024 + gCol] = v[r] + bb2;
            }
        }
    }
}

// ---------------- fused: gemm1 (v@w_v^T -> vvT) interleaved with softmax+replicate ----------------
// 16896 blocks = 512*33; every 33rd block is a gemm block so compute-bound gemm
// blocks co-reside with BW-bound softmax blocks (overlap ~ max, not sum).
__global__ __launch_bounds__(256) void fused_g1_sm(
    const unsigned short* __restrict__ v_bf, const unsigned short* __restrict__ wv_bf,
    const float* __restrict__ b_v, unsigned short* __restrict__ vvT,
    const float* __restrict__ posi, float* __restrict__ attn_out,
    unsigned short* __restrict__ a_bf) {
    __shared__ unsigned short sAB[8192];
    __shared__ float red[8];
    const int bid = blockIdx.x;
    if (bid % 33 == 0) {
        const int g = bid / 33;  // 0..511
        gemm128_core<1>(v_bf, wv_bf, b_v, vvT, 1024, g >> 3, g & 7, 0, sAB, sAB + 4096);
        return;
    }
    const int blk = bid - 1 - bid / 33;  // 0..16383
    const int h = blk >> 10, i = blk & 1023;
    const int t = threadIdx.x;
    const float4* rowp = (const float4*)(posi + (((size_t)h << 10) + i) * 1024);
    float4 p = rowp[t];
    const int j0 = t << 2;
    float* pf = (float*)&p;
    if (i >= j0 && i < j0 + 4) pf[i - j0] = -1e30f;  // mask diagonal
    float m = fmaxf(fmaxf(pf[0], pf[1]), fmaxf(pf[2], pf[3]));
    m = waveMax(m);
    if ((t & 63) == 0) red[t >> 6] = m;
    __syncthreads();
    m = fmaxf(fmaxf(red[0], red[1]), fmaxf(red[2], red[3]));
    const float e0 = __expf(pf[0] - m), e1 = __expf(pf[1] - m);
    const float e2 = __expf(pf[2] - m), e3 = __expf(pf[3] - m);
    float s = waveSum(e0 + e1 + e2 + e3);
    if ((t & 63) == 0) red[4 + (t >> 6)] = s;
    __syncthreads();
    s = red[4] + red[5] + red[6] + red[7];
    const float inv = 1.0f / s;
    float4 a;
    a.x = e0 * inv; a.y = e1 * inv; a.z = e2 * inv; a.w = e3 * inv;
    float* base = attn_out + (((size_t)h << 3) << 20) + ((size_t)i << 10);
#pragma unroll
    for (int b = 0; b < 8; ++b)
        ((float4*)(base + ((size_t)b << 20)))[t] = a;
    short4v u;
    u[0] = (short)f2bf(a.x); u[1] = (short)f2bf(a.y);
    u[2] = (short)f2bf(a.z); u[3] = (short)f2bf(a.w);
    *(short4v*)(a_bf + ((((size_t)h << 10) + i) << 10) + j0) = u;
}

// ---------------- standalone GEMM wrappers ----------------
__global__ __launch_bounds__(256) void gemm_k2(const unsigned short* __restrict__ A,
                                               const unsigned short* __restrict__ Bt,
                                               unsigned short* __restrict__ X) {
    __shared__ unsigned short sAB[8192];
    const int bh = blockIdx.z;
    gemm128_core<2>(A + (size_t)bh * 1048576, Bt + (size_t)bh * 524288, nullptr, X,
                    1024, blockIdx.y, blockIdx.x, bh, sAB, sAB + 4096);
}

__global__ __launch_bounds__(256) void gemm_k3(const unsigned short* __restrict__ A,
                                               const unsigned short* __restrict__ Bt,
                                               const float* __restrict__ bias,
                                               float* __restrict__ O) {
    __shared__ unsigned short sAB[8192];
    gemm128_core<3>(A, Bt, bias, O, 1024, blockIdx.y, blockIdx.x, 0, sAB, sAB + 4096);
}

// ---------------- in-place row LayerNorm over DM=1024 ----------------
__global__ __launch_bounds__(256) void ln_kernel(float* __restrict__ out,
                                                 const float* __restrict__ g,
                                                 const float* __restrict__ b) {
    __shared__ float red[8];
    const int row = blockIdx.x, t = threadIdx.x;
    float4* p = (float4*)(out + ((size_t)row << 10));
    float4 x = p[t];
    float s = x.x + x.y + x.z + x.w;
    float sq = x.x * x.x + x.y * x.y + x.z * x.z + x.w * x.w;
    s = waveSum(s);
    sq = waveSum(sq);
    if ((t & 63) == 0) { red[t >> 6] = s; red[4 + (t >> 6)] = sq; }
    __syncthreads();
    s = red[0] + red[1] + red[2] + red[3];
    sq = red[4] + red[5] + red[6] + red[7];
    const float mu = s * (1.f / 1024.f);
    const float var = sq * (1.f / 1024.f) - mu * mu;
    const float rinv = rsqrtf(var + 1e-5f);
    const float4 gg = ((const float4*)g)[t];
    const float4 bb = ((const float4*)b)[t];
    x.x = (x.x - mu) * rinv * gg.x + bb.x;
    x.y = (x.y - mu) * rinv * gg.y + bb.y;
    x.z = (x.z - mu) * rinv * gg.z + bb.z;
    x.w = (x.w - mu) * rinv * gg.w + bb.w;
    p[t] = x;
}

extern "C" void kernel_launch(void* const* d_in, const int* in_sizes, int n_in,
                              void* d_out, int out_size, void* d_ws, size_t ws_size,
                              hipStream_t stream) {
    const float* v    = (const float*)d_in[2];
    const float* posi = (const float*)d_in[3];
    const float* w_v  = (const float*)d_in[6];
    const float* b_v  = (const float*)d_in[7];
    const float* w_fc = (const float*)d_in[8];
    const float* b_fc = (const float*)d_in[9];
    const float* ln_g = (const float*)d_in[10];
    const float* ln_b = (const float*)d_in[11];

    float* out = (float*)d_out;                     // [8,1024,1024] fp32
    float* attn_out = out + (size_t)NB * NL * NDM;  // [128,1024,1024] fp32

    char* ws = (char*)d_ws;
    unsigned short* A_bf   = (unsigned short*)(ws);              // [16][1024][1024] bf16  32MB
    unsigned short* v_bf   = (unsigned short*)(ws + 33554432);   // [8192][1024]     bf16  16MB
    unsigned short* wv_bf  = (unsigned short*)(ws + 50331648);   // [1024][1024]     bf16   2MB
    unsigned short* wfc_bf = (unsigned short*)(ws + 52428800);   // [1024][1024]     bf16   2MB
    unsigned short* vvT    = (unsigned short*)(ws + 54525952);   // [16][512][1024]  bf16  16MB
    unsigned short* X      = (unsigned short*)(ws + 71303168);   // [8192][1024]     bf16  16MB

    cvt3<<<10240, 256, 0, stream>>>(v, w_v, w_fc, v_bf, wv_bf, wfc_bf);
    // gemm1 (needs cvt) interleaved with softmax+replicate (independent)
    fused_g1_sm<<<16896, 256, 0, stream>>>(v_bf, wv_bf, b_v, vvT, posi, attn_out, A_bf);
    // ctx: per h: A[h] @ vvT[h]^T -> X[(b*1024+q)][h*64+d]
    gemm_k2<<<dim3(4, 8, 16), 256, 0, stream>>>(A_bf, vvT, X);
    // out = X @ w_fc^T + b_fc (fp32)
    gemm_k3<<<dim3(8, 64, 1), 256, 0, stream>>>(X, wfc_bf, b_fc, out);
    ln_kernel<<<8192, 256, 0, stream>>>(out, ln_g, ln_b);
}

// Round 3
// 285.509 us; speedup vs baseline: 1.0077x; 1.0077x over previous
//
#include <hip/hip_runtime.h>
#include <stdint.h>

#define NH 16
#define NDV 64
#define NDM 1024
#define NB 8
#define NL 1024

typedef __attribute__((ext_vector_type(8))) short short8;
typedef __attribute__((ext_vector_type(4))) short short4v;
typedef __attribute__((ext_vector_type(4))) float f32x4;

static __device__ __forceinline__ unsigned short f2bf(float x) {
    unsigned int u = __builtin_bit_cast(unsigned int, x);
    unsigned int r = (u + 0x7fffu + ((u >> 16) & 1u)) >> 16;
    return (unsigned short)r;
}
static __device__ __forceinline__ float bf2f(unsigned short u) {
    return __builtin_bit_cast(float, (unsigned int)u << 16);
}

static __device__ __forceinline__ float waveMax(float v) {
#pragma unroll
    for (int o = 32; o > 0; o >>= 1) v = fmaxf(v, __shfl_xor(v, o, 64));
    return v;
}
static __device__ __forceinline__ float waveSum(float v) {
#pragma unroll
    for (int o = 32; o > 0; o >>= 1) v += __shfl_xor(v, o, 64);
    return v;
}

// async global->LDS, 16B per lane (wave writes 1KB contiguous at ldsptr)
static __device__ __forceinline__ void gload_lds16(const void* g, void* l) {
    __builtin_amdgcn_global_load_lds((const __attribute__((address_space(1))) void*)g,
                                     (__attribute__((address_space(3))) void*)l, 16, 0, 0);
}

// ---------------- phase A: softmax->bf16 A + fp32->bf16 converts ----------------
// blocks [0,16384): softmax row (h,i) -> a_bf only
// blocks [16384, 26624): cvt of v / w_v / w_fc
__global__ __launch_bounds__(256) void phaseA(
    const float* __restrict__ posi, unsigned short* __restrict__ a_bf,
    const float* __restrict__ v, const float* __restrict__ wv, const float* __restrict__ wfc,
    unsigned short* __restrict__ v_bf, unsigned short* __restrict__ wv_bf,
    unsigned short* __restrict__ wfc_bf) {
    __shared__ float red[8];
    const int bid = blockIdx.x;
    const int t = threadIdx.x;
    if (bid < 16384) {
        const int h = bid >> 10, i = bid & 1023;
        const float4* rowp = (const float4*)(posi + (((size_t)h << 10) + i) * 1024);
        float4 p = rowp[t];
        const int j0 = t << 2;
        float* pf = (float*)&p;
        if (i >= j0 && i < j0 + 4) pf[i - j0] = -1e30f;  // mask diagonal
        float m = fmaxf(fmaxf(pf[0], pf[1]), fmaxf(pf[2], pf[3]));
        m = waveMax(m);
        if ((t & 63) == 0) red[t >> 6] = m;
        __syncthreads();
        m = fmaxf(fmaxf(red[0], red[1]), fmaxf(red[2], red[3]));
        const float e0 = __expf(pf[0] - m), e1 = __expf(pf[1] - m);
        const float e2 = __expf(pf[2] - m), e3 = __expf(pf[3] - m);
        float s = waveSum(e0 + e1 + e2 + e3);
        if ((t & 63) == 0) red[4 + (t >> 6)] = s;
        __syncthreads();
        s = red[4] + red[5] + red[6] + red[7];
        const float inv = 1.0f / s;
        short4v u;
        u[0] = (short)f2bf(e0 * inv); u[1] = (short)f2bf(e1 * inv);
        u[2] = (short)f2bf(e2 * inv); u[3] = (short)f2bf(e3 * inv);
        *(short4v*)(a_bf + ((((size_t)h << 10) + i) << 10) + j0) = u;
    } else {
        int b = bid - 16384;
        const float* src;
        unsigned short* dst;
        if (b < 8192)      { src = v;   dst = v_bf; }
        else if (b < 9216) { src = wv;  dst = wv_bf;  b -= 8192; }
        else               { src = wfc; dst = wfc_bf; b -= 9216; }
        const size_t idx = ((size_t)b * 256 + t) << 2;
        const float4 x = *(const float4*)(src + idx);
        short4v u;
        u[0] = (short)f2bf(x.x); u[1] = (short)f2bf(x.y);
        u[2] = (short)f2bf(x.z); u[3] = (short)f2bf(x.w);
        *(short4v*)(dst + idx) = u;
    }
}

// ---------------- 128x128 MFMA GEMM core: C = A[M,K] @ Bt[N,K]^T ----------------
template <int EPI>
static __device__ __forceinline__ void gemm128_core(
    const unsigned short* __restrict__ A,
    const unsigned short* __restrict__ Bt,
    const float* __restrict__ bias,
    void* __restrict__ Cout,
    const int K, const int tm, const int tn, const int bh,
    unsigned short* sA, unsigned short* sB) {
    const int tid = threadIdx.x;
    const int lane = tid & 63;
    const int w = tid >> 6;
    const int wr = w >> 1, wc = w & 1;

    const unsigned short* Ab = A + (size_t)tm * 128 * K;
    const unsigned short* Bb = Bt + (size_t)tn * 128 * K;

    const int r0 = w * 32 + (lane >> 2);
    const int ch = lane & 3;
    const int so = ((ch ^ ((r0 >> 1) & 3)) << 3);  // pre-swizzled source col (shorts)
    const unsigned short* gA0 = Ab + (size_t)r0 * K + so;
    const unsigned short* gA1 = Ab + (size_t)(r0 + 16) * K + so;
    const unsigned short* gB0 = Bb + (size_t)r0 * K + so;
    const unsigned short* gB1 = Bb + (size_t)(r0 + 16) * K + so;
    unsigned short* lA0 = sA + w * 1024;
    unsigned short* lA1 = lA0 + 512;
    unsigned short* lB0 = sB + w * 1024;
    unsigned short* lB1 = lB0 + 512;

    const int c = lane >> 4;
    int offA[4], offB[4];
#pragma unroll
    for (int f = 0; f < 4; ++f) {
        const int fra = wr * 64 + f * 16 + (lane & 15);
        offA[f] = fra * 32 + ((c ^ ((fra >> 1) & 3)) << 3);
        const int frb = wc * 64 + f * 16 + (lane & 15);
        offB[f] = frb * 32 + ((c ^ ((frb >> 1) & 3)) << 3);
    }

    f32x4 acc[4][4];
#pragma unroll
    for (int i = 0; i < 4; ++i)
#pragma unroll
        for (int j = 0; j < 4; ++j) acc[i][j] = (f32x4){0.f, 0.f, 0.f, 0.f};

    for (int kt = 0; kt < K; kt += 32) {
        __syncthreads();
        gload_lds16(gA0 + kt, lA0);
        gload_lds16(gA1 + kt, lA1);
        gload_lds16(gB0 + kt, lB0);
        gload_lds16(gB1 + kt, lB1);
        __syncthreads();

        short8 af[4], bfv[4];
#pragma unroll
        for (int f = 0; f < 4; ++f) af[f] = *(const short8*)&sA[offA[f]];
#pragma unroll
        for (int f = 0; f < 4; ++f) bfv[f] = *(const short8*)&sB[offB[f]];
        __builtin_amdgcn_s_setprio(1);
#pragma unroll
        for (int i = 0; i < 4; ++i)
#pragma unroll
            for (int j = 0; j < 4; ++j)
                acc[i][j] = __builtin_amdgcn_mfma_f32_16x16x32_bf16(af[i], bfv[j], acc[i][j], 0, 0, 0);
        __builtin_amdgcn_s_setprio(0);
    }

#pragma unroll
    for (int i = 0; i < 4; ++i) {
        const int gRow0 = tm * 128 + wr * 64 + i * 16 + ((lane >> 4) << 2);
#pragma unroll
        for (int j = 0; j < 4; ++j) {
            const int gCol = tn * 128 + wc * 64 + j * 16 + (lane & 15);
            f32x4 v = acc[i][j];
            if (EPI == 1) {
                const float bb2 = bias[gCol];
                const int hh = gCol >> 6, dd = gCol & 63;
                const int b = gRow0 >> 10, ll2 = gRow0 & 1023;
                unsigned short* C = (unsigned short*)Cout;
                short4v u;
                u[0] = (short)f2bf(v[0] + bb2);
                u[1] = (short)f2bf(v[1] + bb2);
                u[2] = (short)f2bf(v[2] + bb2);
                u[3] = (short)f2bf(v[3] + bb2);
                *(short4v*)(C + (size_t)hh * 524288 + ((size_t)b * 64 + dd) * 1024 + ll2) = u;
            } else if (EPI == 2) {
                const int b = gCol >> 6, dd = gCol & 63;
                unsigned short* X = (unsigned short*)Cout;
#pragma unroll
                for (int r = 0; r < 4; ++r)
                    X[((size_t)b * 1024 + gRow0 + r) * 1024 + bh * 64 + dd] = f2bf(v[r]);
            } else {
                const float bb2 = bias[gCol];
                float* O = (float*)Cout;
#pragma unroll
                for (int r = 0; r < 4; ++r)
                    O[(size_t)(gRow0 + r) * 1024 + gCol] = v[r] + bb2;
            }
        }
    }
}

// replicate rows [row0, row0+n) of bf16 A into fp32 attn_out (8 batch copies)
static __device__ __forceinline__ void rep_rows(const unsigned short* __restrict__ a_bf,
                                                float* __restrict__ attn_out,
                                                int row0, int n) {
    const int t = threadIdx.x;
    for (int r = 0; r < n; ++r) {
        const int row = row0 + r;
        const int h = row >> 10, i = row & 1023;
        short4v u = *(const short4v*)(a_bf + ((((size_t)h << 10) + i) << 10) + (t << 2));
        float4 x;
        x.x = bf2f((unsigned short)u[0]); x.y = bf2f((unsigned short)u[1]);
        x.z = bf2f((unsigned short)u[2]); x.w = bf2f((unsigned short)u[3]);
        float* base = attn_out + (((size_t)(h << 3)) << 20) + ((size_t)i << 10);
#pragma unroll
        for (int b = 0; b < 8; ++b)
            ((float4*)(base + ((size_t)b << 20)))[t] = x;
    }
}

// ---------------- gemm + replicate, pair-staggered: grid = 512 = 2 blocks/CU ----------------
// blocks 0-255: gemm tile g then replicate chunk g; blocks 256-511: replicate chunk g then gemm tile g
template <int EPI>
__global__ __launch_bounds__(256) void gemm_rep(
    const unsigned short* __restrict__ A, const unsigned short* __restrict__ Bt,
    const float* __restrict__ bias, void* __restrict__ Cout,
    const unsigned short* __restrict__ a_bf, float* __restrict__ attn_out,
    int repBase, int repPerBlk) {
    __shared__ unsigned short sAB[8192];
    const int bid = blockIdx.x;
    const int half = bid >> 8;       // 0 or 1
    const int g = bid & 511;         // but tile id must be unique: use full range
    const int tile = (half == 0) ? (bid & 255) : (256 + (bid & 255));
    const int rrow0 = repBase + tile * repPerBlk;

    int tm, tn, bh = 0;
    const unsigned short* Ag = A;
    const unsigned short* Bg = Bt;
    if (EPI == 2) {
        bh = tile >> 5;
        tm = (tile >> 2) & 7;
        tn = tile & 3;
        Ag += (size_t)bh * 1048576;
        Bg += (size_t)bh * 524288;
    } else {
        tm = tile >> 3;
        tn = tile & 7;
    }
    (void)g;

    if (half == 0) {
        gemm128_core<EPI>(Ag, Bg, bias, Cout, 1024, tm, tn, bh, sAB, sAB + 4096);
        rep_rows(a_bf, attn_out, rrow0, repPerBlk);
    } else {
        rep_rows(a_bf, attn_out, rrow0, repPerBlk);
        __syncthreads();
        gemm128_core<EPI>(Ag, Bg, bias, Cout, 1024, tm, tn, bh, sAB, sAB + 4096);
    }
}

// ---------------- in-place row LayerNorm over DM=1024 ----------------
__global__ __launch_bounds__(256) void ln_kernel(float* __restrict__ out,
                                                 const float* __restrict__ g,
                                                 const float* __restrict__ b) {
    __shared__ float red[8];
    const int row = blockIdx.x, t = threadIdx.x;
    float4* p = (float4*)(out + ((size_t)row << 10));
    float4 x = p[t];
    float s = x.x + x.y + x.z + x.w;
    float sq = x.x * x.x + x.y * x.y + x.z * x.z + x.w * x.w;
    s = waveSum(s);
    sq = waveSum(sq);
    if ((t & 63) == 0) { red[t >> 6] = s; red[4 + (t >> 6)] = sq; }
    __syncthreads();
    s = red[0] + red[1] + red[2] + red[3];
    sq = red[4] + red[5] + red[6] + red[7];
    const float mu = s * (1.f / 1024.f);
    const float var = sq * (1.f / 1024.f) - mu * mu;
    const float rinv = rsqrtf(var + 1e-5f);
    const float4 gg = ((const float4*)g)[t];
    const float4 bb = ((const float4*)b)[t];
    x.x = (x.x - mu) * rinv * gg.x + bb.x;
    x.y = (x.y - mu) * rinv * gg.y + bb.y;
    x.z = (x.z - mu) * rinv * gg.z + bb.z;
    x.w = (x.w - mu) * rinv * gg.w + bb.w;
    p[t] = x;
}

extern "C" void kernel_launch(void* const* d_in, const int* in_sizes, int n_in,
                              void* d_out, int out_size, void* d_ws, size_t ws_size,
                              hipStream_t stream) {
    const float* v    = (const float*)d_in[2];
    const float* posi = (const float*)d_in[3];
    const float* w_v  = (const float*)d_in[6];
    const float* b_v  = (const float*)d_in[7];
    const float* w_fc = (const float*)d_in[8];
    const float* b_fc = (const float*)d_in[9];
    const float* ln_g = (const float*)d_in[10];
    const float* ln_b = (const float*)d_in[11];

    float* out = (float*)d_out;                     // [8,1024,1024] fp32
    float* attn_out = out + (size_t)NB * NL * NDM;  // [128,1024,1024] fp32

    char* ws = (char*)d_ws;
    unsigned short* A_bf   = (unsigned short*)(ws);              // [16][1024][1024] bf16  32MB
    unsigned short* v_bf   = (unsigned short*)(ws + 33554432);   // [8192][1024]     bf16  16MB
    unsigned short* wv_bf  = (unsigned short*)(ws + 50331648);   // [1024][1024]     bf16   2MB
    unsigned short* wfc_bf = (unsigned short*)(ws + 52428800);   // [1024][1024]     bf16   2MB
    unsigned short* vvT    = (unsigned short*)(ws + 54525952);   // [16][512][1024]  bf16  16MB
    unsigned short* X      = (unsigned short*)(ws + 71303168);   // [8192][1024]     bf16  16MB

    // softmax -> A_bf  +  bf16 converts (pure streaming)
    phaseA<<<26624, 256, 0, stream>>>(posi, A_bf, v, w_v, w_fc, v_bf, wv_bf, wfc_bf);
    // gemm1: vvT[h][b*64+d][l] = (v@w_v^T+b_v)^T   | + replicate rows [0,5632)
    gemm_rep<1><<<512, 256, 0, stream>>>(v_bf, wv_bf, b_v, vvT, A_bf, attn_out, 0, 11);
    // gemm2: X[(b*1024+q)][h*64+d] = A[h]@vvT[h]^T | + replicate rows [5632,11264)
    gemm_rep<2><<<512, 256, 0, stream>>>(A_bf, vvT, nullptr, X, A_bf, attn_out, 5632, 11);
    // gemm3: out = X@w_fc^T + b_fc (fp32)          | + replicate rows [11264,16384)
    gemm_rep<3><<<512, 256, 0, stream>>>(X, wfc_bf, b_fc, out, A_bf, attn_out, 11264, 10);
    ln_kernel<<<8192, 256, 0, stream>>>(out, ln_g, ln_b);
}

// Round 4
// 252.181 us; speedup vs baseline: 1.1409x; 1.1322x over previous
//
#include <hip/hip_runtime.h>
#include <stdint.h>

#define NH 16
#define NDV 64
#define NDM 1024
#define NB 8
#define NL 1024

typedef __attribute__((ext_vector_type(8))) short short8;
typedef __attribute__((ext_vector_type(4))) short short4v;
typedef __attribute__((ext_vector_type(4))) float f32x4;

static __device__ __forceinline__ unsigned short f2bf(float x) {
    unsigned int u = __builtin_bit_cast(unsigned int, x);
    unsigned int r = (u + 0x7fffu + ((u >> 16) & 1u)) >> 16;
    return (unsigned short)r;
}

static __device__ __forceinline__ float waveMax(float v) {
#pragma unroll
    for (int o = 32; o > 0; o >>= 1) v = fmaxf(v, __shfl_xor(v, o, 64));
    return v;
}
static __device__ __forceinline__ float waveSum(float v) {
#pragma unroll
    for (int o = 32; o > 0; o >>= 1) v += __shfl_xor(v, o, 64);
    return v;
}

// async global->LDS, 16B per lane (wave writes 1KB contiguous at ldsptr)
static __device__ __forceinline__ void gload_lds16(const void* g, void* l) {
    __builtin_amdgcn_global_load_lds((const __attribute__((address_space(1))) void*)g,
                                     (__attribute__((address_space(3))) void*)l, 16, 0, 0);
}

// ---------------- phase A: softmax+replicate (fp32 out + bf16) + converts ----------------
// blocks [0,16384): softmax row (h,i) -> attn_out fp32 x8 + a_bf
// blocks [16384,26624): fp32->bf16 cvt of v / w_v / w_fc
__global__ __launch_bounds__(256) void phaseA(
    const float* __restrict__ posi, float* __restrict__ attn_out,
    unsigned short* __restrict__ a_bf,
    const float* __restrict__ v, const float* __restrict__ wv, const float* __restrict__ wfc,
    unsigned short* __restrict__ v_bf, unsigned short* __restrict__ wv_bf,
    unsigned short* __restrict__ wfc_bf) {
    __shared__ float red[8];
    const int bid = blockIdx.x;
    const int t = threadIdx.x;
    if (bid < 16384) {
        const int h = bid >> 10, i = bid & 1023;
        const float4* rowp = (const float4*)(posi + (((size_t)h << 10) + i) * 1024);
        float4 p = rowp[t];
        const int j0 = t << 2;
        float* pf = (float*)&p;
        if (i >= j0 && i < j0 + 4) pf[i - j0] = -1e30f;  // mask diagonal
        float m = fmaxf(fmaxf(pf[0], pf[1]), fmaxf(pf[2], pf[3]));
        m = waveMax(m);
        if ((t & 63) == 0) red[t >> 6] = m;
        __syncthreads();
        m = fmaxf(fmaxf(red[0], red[1]), fmaxf(red[2], red[3]));
        const float e0 = __expf(pf[0] - m), e1 = __expf(pf[1] - m);
        const float e2 = __expf(pf[2] - m), e3 = __expf(pf[3] - m);
        float s = waveSum(e0 + e1 + e2 + e3);
        if ((t & 63) == 0) red[4 + (t >> 6)] = s;
        __syncthreads();
        s = red[4] + red[5] + red[6] + red[7];
        const float inv = 1.0f / s;
        float4 a;
        a.x = e0 * inv; a.y = e1 * inv; a.z = e2 * inv; a.w = e3 * inv;
        float* base = attn_out + (((size_t)(h << 3)) << 20) + ((size_t)i << 10);
#pragma unroll
        for (int b = 0; b < 8; ++b)
            ((float4*)(base + ((size_t)b << 20)))[t] = a;
        short4v u;
        u[0] = (short)f2bf(a.x); u[1] = (short)f2bf(a.y);
        u[2] = (short)f2bf(a.z); u[3] = (short)f2bf(a.w);
        *(short4v*)(a_bf + ((((size_t)h << 10) + i) << 10) + j0) = u;
    } else {
        int b = bid - 16384;
        const float* src;
        unsigned short* dst;
        if (b < 8192)      { src = v;   dst = v_bf; }
        else if (b < 9216) { src = wv;  dst = wv_bf;  b -= 8192; }
        else               { src = wfc; dst = wfc_bf; b -= 9216; }
        const size_t idx = ((size_t)b * 256 + t) << 2;
        const float4 x = *(const float4*)(src + idx);
        short4v u;
        u[0] = (short)f2bf(x.x); u[1] = (short)f2bf(x.y);
        u[2] = (short)f2bf(x.z); u[3] = (short)f2bf(x.w);
        *(short4v*)(dst + idx) = u;
    }
}

// ---------------- 128x128 MFMA GEMM core, 2-phase double-buffered ----------------
// C = A[M,K] @ Bt[N,K]^T. global_load_lds(16B) staging into 2 LDS buffers;
// stage(t+1) issued BEFORE compute(t); ONE barrier per K-step (its vmcnt(0)
// drain is covered by 8 ds_read + 16 MFMA). Chunk-XOR swizzle on global source
// + ds_read addr (LDS dest linear, per gload_lds constraint).
template <int EPI>
static __device__ __forceinline__ void gemm128_core(
    const unsigned short* __restrict__ A,
    const unsigned short* __restrict__ Bt,
    const float* __restrict__ bias,
    void* __restrict__ Cout,
    const int K, const int tm, const int tn, const int bh,
    unsigned short* sA, unsigned short* sB) {  // each 2*4096 shorts
    const int tid = threadIdx.x;
    const int lane = tid & 63;
    const int w = tid >> 6;
    const int wr = w >> 1, wc = w & 1;

    const unsigned short* Ab = A + (size_t)tm * 128 * K;
    const unsigned short* Bb = Bt + (size_t)tn * 128 * K;

    // staging: wave w covers rows [w*32, w*32+32); lane -> rows r0, r0+16; chunk = lane&3
    const int r0 = w * 32 + (lane >> 2);
    const int ch = lane & 3;
    const int so = ((ch ^ ((r0 >> 1) & 3)) << 3);  // pre-swizzled source col (shorts)
    const unsigned short* gA0 = Ab + (size_t)r0 * K + so;
    const unsigned short* gA1 = Ab + (size_t)(r0 + 16) * K + so;  // same swizzle key
    const unsigned short* gB0 = Bb + (size_t)r0 * K + so;
    const unsigned short* gB1 = Bb + (size_t)(r0 + 16) * K + so;
    const int ldsOff = w * 1024;

    // fragment ds_read offsets (swizzled), within one buffer
    const int c = lane >> 4;
    int offA[4], offB[4];
#pragma unroll
    for (int f = 0; f < 4; ++f) {
        const int fra = wr * 64 + f * 16 + (lane & 15);
        offA[f] = fra * 32 + ((c ^ ((fra >> 1) & 3)) << 3);
        const int frb = wc * 64 + f * 16 + (lane & 15);
        offB[f] = frb * 32 + ((c ^ ((frb >> 1) & 3)) << 3);
    }

    f32x4 acc[4][4];
#pragma unroll
    for (int i = 0; i < 4; ++i)
#pragma unroll
        for (int j = 0; j < 4; ++j) acc[i][j] = (f32x4){0.f, 0.f, 0.f, 0.f};

    const int nst = K >> 5;
    // prologue: stage K-step 0 into buffer 0
    {
        unsigned short* lA = sA + ldsOff;
        unsigned short* lB = sB + ldsOff;
        gload_lds16(gA0, lA);
        gload_lds16(gA1, lA + 512);
        gload_lds16(gB0, lB);
        gload_lds16(gB1, lB + 512);
    }
    __syncthreads();  // drains vmcnt(0): buffer 0 ready

    int cur = 0;
    for (int t = 0; t < nst; ++t) {
        if (t + 1 < nst) {  // issue next stage FIRST (prefetch)
            const int kt = (t + 1) << 5;
            unsigned short* lA = sA + ((cur ^ 1) << 12) + ldsOff;
            unsigned short* lB = sB + ((cur ^ 1) << 12) + ldsOff;
            gload_lds16(gA0 + kt, lA);
            gload_lds16(gA1 + kt, lA + 512);
            gload_lds16(gB0 + kt, lB);
            gload_lds16(gB1 + kt, lB + 512);
        }
        const unsigned short* bA = sA + (cur << 12);
        const unsigned short* bB = sB + (cur << 12);
        short8 af[4], bfv[4];
#pragma unroll
        for (int f = 0; f < 4; ++f) af[f] = *(const short8*)&bA[offA[f]];
#pragma unroll
        for (int f = 0; f < 4; ++f) bfv[f] = *(const short8*)&bB[offB[f]];
        __builtin_amdgcn_s_setprio(1);
#pragma unroll
        for (int i = 0; i < 4; ++i)
#pragma unroll
            for (int j = 0; j < 4; ++j)
                acc[i][j] = __builtin_amdgcn_mfma_f32_16x16x32_bf16(af[i], bfv[j], acc[i][j], 0, 0, 0);
        __builtin_amdgcn_s_setprio(0);
        if (t + 1 < nst) __syncthreads();  // vmcnt(0) drain = wait for prefetched stage
        cur ^= 1;
    }

#pragma unroll
    for (int i = 0; i < 4; ++i) {
        const int gRow0 = tm * 128 + wr * 64 + i * 16 + ((lane >> 4) << 2);
#pragma unroll
        for (int j = 0; j < 4; ++j) {
            const int gCol = tn * 128 + wc * 64 + j * 16 + (lane & 15);
            f32x4 v = acc[i][j];
            if (EPI == 1) {
                const float bb2 = bias[gCol];
                const int hh = gCol >> 6, dd = gCol & 63;
                const int b = gRow0 >> 10, ll2 = gRow0 & 1023;
                unsigned short* C = (unsigned short*)Cout;
                short4v u;
                u[0] = (short)f2bf(v[0] + bb2);
                u[1] = (short)f2bf(v[1] + bb2);
                u[2] = (short)f2bf(v[2] + bb2);
                u[3] = (short)f2bf(v[3] + bb2);
                *(short4v*)(C + (size_t)hh * 524288 + ((size_t)b * 64 + dd) * 1024 + ll2) = u;
            } else if (EPI == 2) {
                const int b = gCol >> 6, dd = gCol & 63;
                unsigned short* X = (unsigned short*)Cout;
#pragma unroll
                for (int r = 0; r < 4; ++r)
                    X[((size_t)b * 1024 + gRow0 + r) * 1024 + bh * 64 + dd] = f2bf(v[r]);
            } else {
                const float bb2 = bias[gCol];
                float* O = (float*)Cout;
#pragma unroll
                for (int r = 0; r < 4; ++r)
                    O[(size_t)(gRow0 + r) * 1024 + gCol] = v[r] + bb2;
            }
        }
    }
}

// ---------------- GEMM wrappers (XCD-swizzled block id, 512 = 8 x 64) ----------------
__global__ __launch_bounds__(256) void gemm_k1(const unsigned short* __restrict__ A,
                                               const unsigned short* __restrict__ Bt,
                                               const float* __restrict__ bias,
                                               unsigned short* __restrict__ C) {
    __shared__ unsigned short sA[8192], sB[8192];
    const int s = (blockIdx.x & 7) * 64 + (blockIdx.x >> 3);
    gemm128_core<1>(A, Bt, bias, C, 1024, s >> 3, s & 7, 0, sA, sB);
}

__global__ __launch_bounds__(256) void gemm_k2(const unsigned short* __restrict__ A,
                                               const unsigned short* __restrict__ Bt,
                                               unsigned short* __restrict__ X) {
    __shared__ unsigned short sA[8192], sB[8192];
    const int s = (blockIdx.x & 7) * 64 + (blockIdx.x >> 3);
    const int bh = s >> 5;
    gemm128_core<2>(A + (size_t)bh * 1048576, Bt + (size_t)bh * 524288, nullptr, X,
                    1024, (s >> 2) & 7, s & 3, bh, sA, sB);
}

__global__ __launch_bounds__(256) void gemm_k3(const unsigned short* __restrict__ A,
                                               const unsigned short* __restrict__ Bt,
                                               const float* __restrict__ bias,
                                               float* __restrict__ O) {
    __shared__ unsigned short sA[8192], sB[8192];
    const int s = (blockIdx.x & 7) * 64 + (blockIdx.x >> 3);
    gemm128_core<3>(A, Bt, bias, O, 1024, s >> 3, s & 7, 0, sA, sB);
}

// ---------------- in-place row LayerNorm over DM=1024 ----------------
__global__ __launch_bounds__(256) void ln_kernel(float* __restrict__ out,
                                                 const float* __restrict__ g,
                                                 const float* __restrict__ b) {
    __shared__ float red[8];
    const int row = blockIdx.x, t = threadIdx.x;
    float4* p = (float4*)(out + ((size_t)row << 10));
    float4 x = p[t];
    float s = x.x + x.y + x.z + x.w;
    float sq = x.x * x.x + x.y * x.y + x.z * x.z + x.w * x.w;
    s = waveSum(s);
    sq = waveSum(sq);
    if ((t & 63) == 0) { red[t >> 6] = s; red[4 + (t >> 6)] = sq; }
    __syncthreads();
    s = red[0] + red[1] + red[2] + red[3];
    sq = red[4] + red[5] + red[6] + red[7];
    const float mu = s * (1.f / 1024.f);
    const float var = sq * (1.f / 1024.f) - mu * mu;
    const float rinv = rsqrtf(var + 1e-5f);
    const float4 gg = ((const float4*)g)[t];
    const float4 bb = ((const float4*)b)[t];
    x.x = (x.x - mu) * rinv * gg.x + bb.x;
    x.y = (x.y - mu) * rinv * gg.y + bb.y;
    x.z = (x.z - mu) * rinv * gg.z + bb.z;
    x.w = (x.w - mu) * rinv * gg.w + bb.w;
    p[t] = x;
}

extern "C" void kernel_launch(void* const* d_in, const int* in_sizes, int n_in,
                              void* d_out, int out_size, void* d_ws, size_t ws_size,
                              hipStream_t stream) {
    const float* v    = (const float*)d_in[2];
    const float* posi = (const float*)d_in[3];
    const float* w_v  = (const float*)d_in[6];
    const float* b_v  = (const float*)d_in[7];
    const float* w_fc = (const float*)d_in[8];
    const float* b_fc = (const float*)d_in[9];
    const float* ln_g = (const float*)d_in[10];
    const float* ln_b = (const float*)d_in[11];

    float* out = (float*)d_out;                     // [8,1024,1024] fp32
    float* attn_out = out + (size_t)NB * NL * NDM;  // [128,1024,1024] fp32

    char* ws = (char*)d_ws;
    unsigned short* A_bf   = (unsigned short*)(ws);              // [16][1024][1024] bf16  32MB
    unsigned short* v_bf   = (unsigned short*)(ws + 33554432);   // [8192][1024]     bf16  16MB
    unsigned short* wv_bf  = (unsigned short*)(ws + 50331648);   // [1024][1024]     bf16   2MB
    unsigned short* wfc_bf = (unsigned short*)(ws + 52428800);   // [1024][1024]     bf16   2MB
    unsigned short* vvT    = (unsigned short*)(ws + 54525952);   // [16][512][1024]  bf16  16MB
    unsigned short* X      = (unsigned short*)(ws + 71303168);   // [8192][1024]     bf16  16MB

    // softmax -> attn fp32 (x8) + A_bf, plus bf16 converts (pure streaming, write-floor)
    phaseA<<<26624, 256, 0, stream>>>(posi, attn_out, A_bf, v, w_v, w_fc, v_bf, wv_bf, wfc_bf);
    // gemm1: vvT[h][b*64+d][l] = (v@w_v^T+b_v)^T
    gemm_k1<<<512, 256, 0, stream>>>(v_bf, wv_bf, b_v, vvT);
    // gemm2: X[(b*1024+q)][h*64+d] = A[h]@vvT[h]^T
    gemm_k2<<<512, 256, 0, stream>>>(A_bf, vvT, X);
    // gemm3: out = X@w_fc^T + b_fc (fp32)
    gemm_k3<<<512, 256, 0, stream>>>(X, wfc_bf, b_fc, out);
    ln_kernel<<<8192, 256, 0, stream>>>(out, ln_g, ln_b);
}

// Round 5
// 248.482 us; speedup vs baseline: 1.1579x; 1.0149x over previous
//
#include <hip/hip_runtime.h>
#include <stdint.h>

#define NH 16
#define NDV 64
#define NDM 1024
#define NB 8
#define NL 1024

typedef __attribute__((ext_vector_type(8))) short short8;
typedef __attribute__((ext_vector_type(4))) short short4v;
typedef __attribute__((ext_vector_type(4))) float f32x4;

static __device__ __forceinline__ unsigned short f2bf(float x) {
    unsigned int u = __builtin_bit_cast(unsigned int, x);
    unsigned int r = (u + 0x7fffu + ((u >> 16) & 1u)) >> 16;
    return (unsigned short)r;
}

static __device__ __forceinline__ float waveMax(float v) {
#pragma unroll
    for (int o = 32; o > 0; o >>= 1) v = fmaxf(v, __shfl_xor(v, o, 64));
    return v;
}
static __device__ __forceinline__ float waveSum(float v) {
#pragma unroll
    for (int o = 32; o > 0; o >>= 1) v += __shfl_xor(v, o, 64);
    return v;
}

// async global->LDS, 16B per lane (wave writes 1KB contiguous at ldsptr)
static __device__ __forceinline__ void gload_lds16(const void* g, void* l) {
    __builtin_amdgcn_global_load_lds((const __attribute__((address_space(1))) void*)g,
                                     (__attribute__((address_space(3))) void*)l, 16, 0, 0);
}

// ---------------- phase A: softmax+replicate (fp32 out + bf16) + converts ----------------
__global__ __launch_bounds__(256) void phaseA(
    const float* __restrict__ posi, float* __restrict__ attn_out,
    unsigned short* __restrict__ a_bf,
    const float* __restrict__ v, const float* __restrict__ wv, const float* __restrict__ wfc,
    unsigned short* __restrict__ v_bf, unsigned short* __restrict__ wv_bf,
    unsigned short* __restrict__ wfc_bf) {
    __shared__ float red[8];
    const int bid = blockIdx.x;
    const int t = threadIdx.x;
    if (bid < 16384) {
        const int h = bid >> 10, i = bid & 1023;
        const float4* rowp = (const float4*)(posi + (((size_t)h << 10) + i) * 1024);
        float4 p = rowp[t];
        const int j0 = t << 2;
        float* pf = (float*)&p;
        if (i >= j0 && i < j0 + 4) pf[i - j0] = -1e30f;  // mask diagonal
        float m = fmaxf(fmaxf(pf[0], pf[1]), fmaxf(pf[2], pf[3]));
        m = waveMax(m);
        if ((t & 63) == 0) red[t >> 6] = m;
        __syncthreads();
        m = fmaxf(fmaxf(red[0], red[1]), fmaxf(red[2], red[3]));
        const float e0 = __expf(pf[0] - m), e1 = __expf(pf[1] - m);
        const float e2 = __expf(pf[2] - m), e3 = __expf(pf[3] - m);
        float s = waveSum(e0 + e1 + e2 + e3);
        if ((t & 63) == 0) red[4 + (t >> 6)] = s;
        __syncthreads();
        s = red[4] + red[5] + red[6] + red[7];
        const float inv = 1.0f / s;
        float4 a;
        a.x = e0 * inv; a.y = e1 * inv; a.z = e2 * inv; a.w = e3 * inv;
        float* base = attn_out + (((size_t)(h << 3)) << 20) + ((size_t)i << 10);
#pragma unroll
        for (int b = 0; b < 8; ++b)
            ((float4*)(base + ((size_t)b << 20)))[t] = a;
        short4v u;
        u[0] = (short)f2bf(a.x); u[1] = (short)f2bf(a.y);
        u[2] = (short)f2bf(a.z); u[3] = (short)f2bf(a.w);
        *(short4v*)(a_bf + ((((size_t)h << 10) + i) << 10) + j0) = u;
    } else {
        int b = bid - 16384;
        const float* src;
        unsigned short* dst;
        if (b < 8192)      { src = v;   dst = v_bf; }
        else if (b < 9216) { src = wv;  dst = wv_bf;  b -= 8192; }
        else               { src = wfc; dst = wfc_bf; b -= 9216; }
        const size_t idx = ((size_t)b * 256 + t) << 2;
        const float4 x = *(const float4*)(src + idx);
        short4v u;
        u[0] = (short)f2bf(x.x); u[1] = (short)f2bf(x.y);
        u[2] = (short)f2bf(x.z); u[3] = (short)f2bf(x.w);
        *(short4v*)(dst + idx) = u;
    }
}

// ---------------- 128x128 MFMA GEMM core, triple-buffered, counted vmcnt ----------------
// C = A[M,K] @ Bt[N,K]^T. Pipeline: stages t+1,t+2 in flight; per K-step:
//   s_waitcnt vmcnt(4) (stage t landed, t+1 still flying) -> raw s_barrier ->
//   issue stage t+2 -> ds_read frags + 16 MFMA.  Never drains vmcnt to 0 in loop.
template <int EPI>
static __device__ __forceinline__ void gemm128_core(
    const unsigned short* __restrict__ A,
    const unsigned short* __restrict__ Bt,
    const float* __restrict__ bias,
    void* __restrict__ Cout,
    const int K, const int tm, const int tn, const int bh,
    unsigned short* sA, unsigned short* sB) {  // each 3*4096 shorts
    const int tid = threadIdx.x;
    const int lane = tid & 63;
    const int w = tid >> 6;
    const int wr = w >> 1, wc = w & 1;

    const unsigned short* Ab = A + (size_t)tm * 128 * K;
    const unsigned short* Bb = Bt + (size_t)tn * 128 * K;

    // staging: wave w covers rows [w*32, w*32+32); lane -> rows r0, r0+16; chunk = lane&3
    const int r0 = w * 32 + (lane >> 2);
    const int ch = lane & 3;
    const int so = ((ch ^ ((r0 >> 1) & 3)) << 3);  // pre-swizzled source col (shorts)
    const unsigned short* gA0 = Ab + (size_t)r0 * K + so;
    const unsigned short* gA1 = Ab + (size_t)(r0 + 16) * K + so;
    const unsigned short* gB0 = Bb + (size_t)r0 * K + so;
    const unsigned short* gB1 = Bb + (size_t)(r0 + 16) * K + so;
    const int ldsOff = w * 1024;

    // fragment ds_read offsets (swizzled), within one buffer
    const int c = lane >> 4;
    int offA[4], offB[4];
#pragma unroll
    for (int f = 0; f < 4; ++f) {
        const int fra = wr * 64 + f * 16 + (lane & 15);
        offA[f] = fra * 32 + ((c ^ ((fra >> 1) & 3)) << 3);
        const int frb = wc * 64 + f * 16 + (lane & 15);
        offB[f] = frb * 32 + ((c ^ ((frb >> 1) & 3)) << 3);
    }

    f32x4 acc[4][4];
#pragma unroll
    for (int i = 0; i < 4; ++i)
#pragma unroll
        for (int j = 0; j < 4; ++j) acc[i][j] = (f32x4){0.f, 0.f, 0.f, 0.f};

    const int nst = K >> 5;  // K-steps of 32

    // prologue: stage steps 0 and 1 into buffers 0 and 1
#pragma unroll
    for (int p = 0; p < 2; ++p) {
        unsigned short* lA = sA + (p << 12) + ldsOff;
        unsigned short* lB = sB + (p << 12) + ldsOff;
        const int kt = p << 5;
        gload_lds16(gA0 + kt, lA);
        gload_lds16(gA1 + kt, lA + 512);
        gload_lds16(gB0 + kt, lB);
        gload_lds16(gB1 + kt, lB + 512);
    }

    int cur = 0;  // t % 3
    for (int t = 0; t < nst; ++t) {
        if (t + 1 < nst) {
            asm volatile("s_waitcnt vmcnt(4)" ::: "memory");  // stage(t) landed; t+1 in flight
        } else {
            asm volatile("s_waitcnt vmcnt(0)" ::: "memory");
        }
        __builtin_amdgcn_s_barrier();            // all waves' stage(t) landed; all done reading buf[(t-1)%3]
        __builtin_amdgcn_sched_barrier(0);
        if (t + 2 < nst) {                       // stage t+2 into buf[(t+2)%3] == buf[(t-1)%3]
            const int sb = (cur + 2 >= 3) ? cur - 1 : cur + 2;
            unsigned short* lA = sA + (sb << 12) + ldsOff;
            unsigned short* lB = sB + (sb << 12) + ldsOff;
            const int kt = (t + 2) << 5;
            gload_lds16(gA0 + kt, lA);
            gload_lds16(gA1 + kt, lA + 512);
            gload_lds16(gB0 + kt, lB);
            gload_lds16(gB1 + kt, lB + 512);
        }
        const unsigned short* bA = sA + (cur << 12);
        const unsigned short* bB = sB + (cur << 12);
        short8 af[4], bfv[4];
#pragma unroll
        for (int f = 0; f < 4; ++f) af[f] = *(const short8*)&bA[offA[f]];
#pragma unroll
        for (int f = 0; f < 4; ++f) bfv[f] = *(const short8*)&bB[offB[f]];
        __builtin_amdgcn_s_setprio(1);
#pragma unroll
        for (int i = 0; i < 4; ++i)
#pragma unroll
            for (int j = 0; j < 4; ++j)
                acc[i][j] = __builtin_amdgcn_mfma_f32_16x16x32_bf16(af[i], bfv[j], acc[i][j], 0, 0, 0);
        __builtin_amdgcn_s_setprio(0);
        cur = (cur == 2) ? 0 : cur + 1;
    }

#pragma unroll
    for (int i = 0; i < 4; ++i) {
        const int gRow0 = tm * 128 + wr * 64 + i * 16 + ((lane >> 4) << 2);
#pragma unroll
        for (int j = 0; j < 4; ++j) {
            const int gCol = tn * 128 + wc * 64 + j * 16 + (lane & 15);
            f32x4 v = acc[i][j];
            if (EPI == 1) {
                const float bb2 = bias[gCol];
                const int hh = gCol >> 6, dd = gCol & 63;
                const int b = gRow0 >> 10, ll2 = gRow0 & 1023;
                unsigned short* C = (unsigned short*)Cout;
                short4v u;
                u[0] = (short)f2bf(v[0] + bb2);
                u[1] = (short)f2bf(v[1] + bb2);
                u[2] = (short)f2bf(v[2] + bb2);
                u[3] = (short)f2bf(v[3] + bb2);
                *(short4v*)(C + (size_t)hh * 524288 + ((size_t)b * 64 + dd) * 1024 + ll2) = u;
            } else if (EPI == 2) {
                const int b = gCol >> 6, dd = gCol & 63;
                unsigned short* X = (unsigned short*)Cout;
#pragma unroll
                for (int r = 0; r < 4; ++r)
                    X[((size_t)b * 1024 + gRow0 + r) * 1024 + bh * 64 + dd] = f2bf(v[r]);
            } else {
                const float bb2 = bias[gCol];
                float* O = (float*)Cout;
#pragma unroll
                for (int r = 0; r < 4; ++r)
                    O[(size_t)(gRow0 + r) * 1024 + gCol] = v[r] + bb2;
            }
        }
    }
}

// ---------------- GEMM wrappers (XCD-swizzled block id, 512 = 8 x 64) ----------------
__global__ __launch_bounds__(256) void gemm_k1(const unsigned short* __restrict__ A,
                                               const unsigned short* __restrict__ Bt,
                                               const float* __restrict__ bias,
                                               unsigned short* __restrict__ C) {
    __shared__ unsigned short sA[12288], sB[12288];
    const int s = (blockIdx.x & 7) * 64 + (blockIdx.x >> 3);
    gemm128_core<1>(A, Bt, bias, C, 1024, s >> 3, s & 7, 0, sA, sB);
}

__global__ __launch_bounds__(256) void gemm_k2(const unsigned short* __restrict__ A,
                                               const unsigned short* __restrict__ Bt,
                                               unsigned short* __restrict__ X) {
    __shared__ unsigned short sA[12288], sB[12288];
    const int s = (blockIdx.x & 7) * 64 + (blockIdx.x >> 3);
    const int bh = s >> 5;
    gemm128_core<2>(A + (size_t)bh * 1048576, Bt + (size_t)bh * 524288, nullptr, X,
                    1024, (s >> 2) & 7, s & 3, bh, sA, sB);
}

__global__ __launch_bounds__(256) void gemm_k3(const unsigned short* __restrict__ A,
                                               const unsigned short* __restrict__ Bt,
                                               const float* __restrict__ bias,
                                               float* __restrict__ O) {
    __shared__ unsigned short sA[12288], sB[12288];
    const int s = (blockIdx.x & 7) * 64 + (blockIdx.x >> 3);
    gemm128_core<3>(A, Bt, bias, O, 1024, s >> 3, s & 7, 0, sA, sB);
}

// ---------------- in-place row LayerNorm over DM=1024 ----------------
__global__ __launch_bounds__(256) void ln_kernel(float* __restrict__ out,
                                                 const float* __restrict__ g,
                                                 const float* __restrict__ b) {
    __shared__ float red[8];
    const int row = blockIdx.x, t = threadIdx.x;
    float4* p = (float4*)(out + ((size_t)row << 10));
    float4 x = p[t];
    float s = x.x + x.y + x.z + x.w;
    float sq = x.x * x.x + x.y * x.y + x.z * x.z + x.w * x.w;
    s = waveSum(s);
    sq = waveSum(sq);
    if ((t & 63) == 0) { red[t >> 6] = s; red[4 + (t >> 6)] = sq; }
    __syncthreads();
    s = red[0] + red[1] + red[2] + red[3];
    sq = red[4] + red[5] + red[6] + red[7];
    const float mu = s * (1.f / 1024.f);
    const float var = sq * (1.f / 1024.f) - mu * mu;
    const float rinv = rsqrtf(var + 1e-5f);
    const float4 gg = ((const float4*)g)[t];
    const float4 bb = ((const float4*)b)[t];
    x.x = (x.x - mu) * rinv * gg.x + bb.x;
    x.y = (x.y - mu) * rinv * gg.y + bb.y;
    x.z = (x.z - mu) * rinv * gg.z + bb.z;
    x.w = (x.w - mu) * rinv * gg.w + bb.w;
    p[t] = x;
}

extern "C" void kernel_launch(void* const* d_in, const int* in_sizes, int n_in,
                              void* d_out, int out_size, void* d_ws, size_t ws_size,
                              hipStream_t stream) {
    const float* v    = (const float*)d_in[2];
    const float* posi = (const float*)d_in[3];
    const float* w_v  = (const float*)d_in[6];
    const float* b_v  = (const float*)d_in[7];
    const float* w_fc = (const float*)d_in[8];
    const float* b_fc = (const float*)d_in[9];
    const float* ln_g = (const float*)d_in[10];
    const float* ln_b = (const float*)d_in[11];

    float* out = (float*)d_out;                     // [8,1024,1024] fp32
    float* attn_out = out + (size_t)NB * NL * NDM;  // [128,1024,1024] fp32

    char* ws = (char*)d_ws;
    unsigned short* A_bf   = (unsigned short*)(ws);              // [16][1024][1024] bf16  32MB
    unsigned short* v_bf   = (unsigned short*)(ws + 33554432);   // [8192][1024]     bf16  16MB
    unsigned short* wv_bf  = (unsigned short*)(ws + 50331648);   // [1024][1024]     bf16   2MB
    unsigned short* wfc_bf = (unsigned short*)(ws + 52428800);   // [1024][1024]     bf16   2MB
    unsigned short* vvT    = (unsigned short*)(ws + 54525952);   // [16][512][1024]  bf16  16MB
    unsigned short* X      = (unsigned short*)(ws + 71303168);   // [8192][1024]     bf16  16MB

    // softmax -> attn fp32 (x8) + A_bf, plus bf16 converts (pure streaming, write-floor)
    phaseA<<<26624, 256, 0, stream>>>(posi, attn_out, A_bf, v, w_v, w_fc, v_bf, wv_bf, wfc_bf);
    // gemm1: vvT[h][b*64+d][l] = (v@w_v^T+b_v)^T
    gemm_k1<<<512, 256, 0, stream>>>(v_bf, wv_bf, b_v, vvT);
    // gemm2: X[(b*1024+q)][h*64+d] = A[h]@vvT[h]^T
    gemm_k2<<<512, 256, 0, stream>>>(A_bf, vvT, X);
    // gemm3: out = X@w_fc^T + b_fc (fp32)
    gemm_k3<<<512, 256, 0, stream>>>(X, wfc_bf, b_fc, out);
    ln_kernel<<<8192, 256, 0, stream>>>(out, ln_g, ln_b);
}